// Round 2
// baseline (2050.192 us; speedup 1.0000x reference)
//
#include <hip/hip_runtime.h>

// PersistentMemory: x[16384,1024], bank[8192,1024]; all fp32 in/out.
// Pipeline: Q/K/Vt GEMMs (bf16 MFMA) -> S-exp GEMM -> PV GEMM -> concat GEMM+residual -> LN.
// Attention is split into two m97-style bf16 NT-GEMMs (global_load_lds staging, XOR-swizzled
// LDS) materializing P (bf16, 256 MB) in ws; falls back to the fused round-1 kernel if ws
// is too small (branch on ws_size is constant across calls -> graph-safe).

typedef __bf16 bf16;
typedef __bf16 bf16x8 __attribute__((ext_vector_type(8)));
typedef float f32x4 __attribute__((ext_vector_type(4)));

static __device__ __forceinline__ f32x4 mfma16(bf16x8 a, bf16x8 b, f32x4 c) {
  return __builtin_amdgcn_mfma_f32_16x16x32_bf16(a, b, c, 0, 0, 0);
}

// async global->LDS, 16B per lane; LDS dest = wave-uniform base + lane*16
#define GLDS16(gp, lp) __builtin_amdgcn_global_load_lds( \
    (const __attribute__((address_space(1))) void*)(gp), \
    (__attribute__((address_space(3))) void*)(lp), 16, 0, 0)

// ---------------------------------------------------------------------------
// bf16 NT-GEMM, m97 structure: C[M,N]=A[M,K]@W[N,K]^T. 128x128 tile, BK=64,
// 256 thr = 4 waves (2x2, wave tile 64x64). Staging: global_load_lds width 16.
// LDS layout: flat 16B slots, slot p holds logical (row=p>>3, cg=(p&7)^(row&7))
// -> frag ds_read_b128 spreads over all 8 col-groups (bank floor), and the
// swizzle is applied on the per-lane GLOBAL address (unconstrained).
// EPI 0: C=exp(acc/32) bf16 (stride N) + rowsum atomicAdd into L.
// EPI 1: C=acc*(1/L[row]) bf16.
// ---------------------------------------------------------------------------
template<int EPI>
__global__ __launch_bounds__(256, 3) void gemm_bb(
    const bf16* __restrict__ A, const bf16* __restrict__ W,
    bf16* __restrict__ C, float* __restrict__ L, int N, int K)
{
  __shared__ bf16 As[128 * 64];
  __shared__ bf16 Bs[128 * 64];
  const int tid = threadIdx.x, lane = tid & 63, wid = tid >> 6;
  const int wm = (wid >> 1) * 64, wn = (wid & 1) * 64;
  const int quad = lane >> 4, l16 = lane & 15;
  const long bm = (long)blockIdx.y * 128, bn = (long)blockIdx.x * 128;

  int prow[4], pcg[4];
#pragma unroll
  for (int i = 0; i < 4; ++i) {
    int p = ((wid * 4 + i) << 6) + lane;   // 16B slot index in [0,1024)
    prow[i] = p >> 3;
    pcg[i] = (p & 7) ^ (prow[i] & 7);
  }

  f32x4 acc[4][4] = {};

  for (int k0 = 0; k0 < K; k0 += 64) {
    __syncthreads();   // previous iteration's frag reads done before overwrite
#pragma unroll
    for (int i = 0; i < 4; ++i) {
      const bf16* ga = A + (size_t)(bm + prow[i]) * K + k0 + pcg[i] * 8;
      GLDS16(ga, (char*)As + ((wid * 4 + i) << 10));
    }
#pragma unroll
    for (int i = 0; i < 4; ++i) {
      const bf16* gb = W + (size_t)(bn + prow[i]) * K + k0 + pcg[i] * 8;
      GLDS16(gb, (char*)Bs + ((wid * 4 + i) << 10));
    }
    __syncthreads();   // staging complete (compiler drains vmcnt before barrier)
#pragma unroll
    for (int kk = 0; kk < 2; ++kk) {
      bf16x8 af[4], bfv[4];
#pragma unroll
      for (int mt = 0; mt < 4; ++mt) {
        const int r = wm + mt * 16 + l16;
        af[mt] = *(const bf16x8*)((const char*)As + (r << 7)
                                  + ((((kk << 2) + quad) ^ (r & 7)) << 4));
      }
#pragma unroll
      for (int nt = 0; nt < 4; ++nt) {
        const int r = wn + nt * 16 + l16;
        bfv[nt] = *(const bf16x8*)((const char*)Bs + (r << 7)
                                   + ((((kk << 2) + quad) ^ (r & 7)) << 4));
      }
#pragma unroll
      for (int mt = 0; mt < 4; ++mt)
#pragma unroll
        for (int nt = 0; nt < 4; ++nt)
          acc[mt][nt] = mfma16(af[mt], bfv[nt], acc[mt][nt]);
    }
  }

#pragma unroll
  for (int mt = 0; mt < 4; ++mt) {
    const long row0 = bm + wm + mt * 16 + quad * 4;
    if (EPI == 0) {
      float rsum[4] = {0.f, 0.f, 0.f, 0.f};
#pragma unroll
      for (int nt = 0; nt < 4; ++nt) {
        const long col = bn + wn + nt * 16 + l16;
#pragma unroll
        for (int r = 0; r < 4; ++r) {
          float p = __expf(acc[mt][nt][r] * 0.03125f);
          rsum[r] += p;
          C[(size_t)(row0 + r) * N + col] = (bf16)p;
        }
      }
#pragma unroll
      for (int s = 1; s < 16; s <<= 1)
#pragma unroll
        for (int r = 0; r < 4; ++r) rsum[r] += __shfl_xor(rsum[r], s, 64);
      if (l16 == 0) {
#pragma unroll
        for (int r = 0; r < 4; ++r) atomicAdd(&L[row0 + r], rsum[r]);
      }
    } else {
      float linv[4];
#pragma unroll
      for (int r = 0; r < 4; ++r) linv[r] = 1.f / L[row0 + r];
#pragma unroll
      for (int nt = 0; nt < 4; ++nt) {
        const long col = bn + wn + nt * 16 + l16;
#pragma unroll
        for (int r = 0; r < 4; ++r)
          C[(size_t)(row0 + r) * N + col] = (bf16)(acc[mt][nt][r] * linv[r]);
      }
    }
  }
}

// ---------------------------------------------------------------------------
// fp32-input NT-GEMM (unchanged from round 1): C[M,N] = A[M,K] @ W[N,K]^T (+bias).
// CONCAT: A columns >=1024 come from A2 (bf16, stride 1024).
// OUT_F32_RES: out = acc + bias + resid (fp32), else bf16 store.
// BIAS_ROW: bias indexed by output row (for the transposed V GEMM).
// ---------------------------------------------------------------------------
template<int BIAS_ROW, int OUT_F32_RES, int CONCAT>
__global__ __launch_bounds__(256, 3) void gemm_nt(
    const float* __restrict__ A, const bf16* __restrict__ A2,
    const float* __restrict__ W, const float* __restrict__ bias,
    const float* __restrict__ resid, void* __restrict__ Cout,
    int M, int N, int K)
{
  __shared__ bf16 As[128][72];
  __shared__ bf16 Bs[128][72];
  const int tid  = threadIdx.x;
  const int lane = tid & 63;
  const int wid  = tid >> 6;
  const int wm   = (wid >> 1) * 64, wn = (wid & 1) * 64;
  const int quad = lane >> 4, l16 = lane & 15;
  const long bm = (long)blockIdx.y * 128, bn = (long)blockIdx.x * 128;
  const int r0 = tid >> 2, cq = (tid & 3) * 16;
  const int lda = CONCAT ? 1024 : K;

  f32x4 acc[4][4] = {};

  for (int k0 = 0; k0 < K; k0 += 64) {
    const bool useb = CONCAT && (k0 >= 1024);
    const int kA = useb ? (k0 - 1024) : k0;
    f32x4 va[2][4], vb[2][4];
    bf16x8 ra[2][2];
    if (useb) {
#pragma unroll
      for (int g = 0; g < 2; ++g) {
        const bf16* p = A2 + (size_t)(bm + r0 + 64 * g) * 1024 + kA + cq;
        ra[g][0] = *(const bf16x8*)p;
        ra[g][1] = *(const bf16x8*)(p + 8);
      }
    } else {
#pragma unroll
      for (int g = 0; g < 2; ++g) {
        const f32x4* p = (const f32x4*)(A + (size_t)(bm + r0 + 64 * g) * lda + kA + cq);
#pragma unroll
        for (int j = 0; j < 4; ++j) va[g][j] = p[j];
      }
    }
#pragma unroll
    for (int g = 0; g < 2; ++g) {
      const f32x4* p = (const f32x4*)(W + (size_t)(bn + r0 + 64 * g) * K + k0 + cq);
#pragma unroll
      for (int j = 0; j < 4; ++j) vb[g][j] = p[j];
    }
    __syncthreads();
#pragma unroll
    for (int g = 0; g < 2; ++g) {
      bf16* dA = &As[r0 + 64 * g][cq];
      if (useb) {
        *(bf16x8*)dA = ra[g][0]; *(bf16x8*)(dA + 8) = ra[g][1];
      } else {
        bf16x8 t0, t1;
#pragma unroll
        for (int j = 0; j < 4; ++j) {
          t0[j] = (bf16)va[g][0][j]; t0[4 + j] = (bf16)va[g][1][j];
          t1[j] = (bf16)va[g][2][j]; t1[4 + j] = (bf16)va[g][3][j];
        }
        *(bf16x8*)dA = t0; *(bf16x8*)(dA + 8) = t1;
      }
      bf16* dB = &Bs[r0 + 64 * g][cq];
      bf16x8 u0, u1;
#pragma unroll
      for (int j = 0; j < 4; ++j) {
        u0[j] = (bf16)vb[g][0][j]; u0[4 + j] = (bf16)vb[g][1][j];
        u1[j] = (bf16)vb[g][2][j]; u1[4 + j] = (bf16)vb[g][3][j];
      }
      *(bf16x8*)dB = u0; *(bf16x8*)(dB + 8) = u1;
    }
    __syncthreads();
#pragma unroll
    for (int kk = 0; kk < 2; ++kk) {
      bf16x8 af[4], bfv[4];
#pragma unroll
      for (int mt = 0; mt < 4; ++mt)
        af[mt] = *(const bf16x8*)&As[wm + mt * 16 + l16][kk * 32 + quad * 8];
#pragma unroll
      for (int nt = 0; nt < 4; ++nt)
        bfv[nt] = *(const bf16x8*)&Bs[wn + nt * 16 + l16][kk * 32 + quad * 8];
#pragma unroll
      for (int mt = 0; mt < 4; ++mt)
#pragma unroll
        for (int nt = 0; nt < 4; ++nt)
          acc[mt][nt] = mfma16(af[mt], bfv[nt], acc[mt][nt]);
    }
  }
#pragma unroll
  for (int mt = 0; mt < 4; ++mt) {
    const long row0 = bm + wm + mt * 16 + quad * 4;
#pragma unroll
    for (int nt = 0; nt < 4; ++nt) {
      const long col = bn + wn + nt * 16 + l16;
      const float bc = BIAS_ROW ? 0.f : bias[col];
#pragma unroll
      for (int r = 0; r < 4; ++r) {
        float v = acc[mt][nt][r] + (BIAS_ROW ? bias[row0 + r] : bc);
        if (OUT_F32_RES) {
          v += resid[(size_t)(row0 + r) * 1024 + col];
          ((float*)Cout)[(size_t)(row0 + r) * N + col] = v;
        } else {
          ((bf16*)Cout)[(size_t)(row0 + r) * N + col] = (bf16)v;
        }
      }
    }
  }
}

// ---------------------------------------------------------------------------
// Fused attention (round-1 version) — FALLBACK ONLY if ws is too small.
// ---------------------------------------------------------------------------
__global__ __launch_bounds__(512, 2) void attn_kernel(
    const bf16* __restrict__ Qb, const bf16* __restrict__ Kb,
    const bf16* __restrict__ Vt, bf16* __restrict__ Rb)
{
  __shared__ bf16 Qs[64][72];
  __shared__ bf16 Ks[128][72];
  __shared__ bf16 Ps[64][136];
  __shared__ float Llds[64];
  const int tid  = threadIdx.x;
  const int lane = tid & 63;
  const int w    = tid >> 6;
  const int quad = lane >> 4, l16 = lane & 15;
  const long qblk = (long)blockIdx.x * 64;
  const int rK = tid >> 2, cqK = (tid & 3) * 16;

  if (tid < 64) Llds[tid] = 0.f;
  __syncthreads();

  f32x4 oacc[4][8] = {};

  for (int c = 0; c < 64; ++c) {
    f32x4 sacc[4] = {};
    for (int ks = 0; ks < 16; ++ks) {
      const int k0 = ks * 64;
      bf16x8 kv0, kv1, qv0, qv1;
      {
        const bf16* p = Kb + (size_t)(c * 128 + rK) * 1024 + k0 + cqK;
        kv0 = *(const bf16x8*)p; kv1 = *(const bf16x8*)(p + 8);
      }
      if (tid < 256) {
        const bf16* p = Qb + (size_t)(qblk + rK) * 1024 + k0 + cqK;
        qv0 = *(const bf16x8*)p; qv1 = *(const bf16x8*)(p + 8);
      }
      __syncthreads();
      { bf16* d = &Ks[rK][cqK]; *(bf16x8*)d = kv0; *(bf16x8*)(d + 8) = kv1; }
      if (tid < 256) { bf16* d = &Qs[rK][cqK]; *(bf16x8*)d = qv0; *(bf16x8*)(d + 8) = qv1; }
      __syncthreads();
#pragma unroll
      for (int kk = 0; kk < 2; ++kk) {
        bf16x8 bfrag = *(const bf16x8*)&Ks[w * 16 + l16][kk * 32 + quad * 8];
#pragma unroll
        for (int mt = 0; mt < 4; ++mt) {
          bf16x8 afrag = *(const bf16x8*)&Qs[mt * 16 + l16][kk * 32 + quad * 8];
          sacc[mt] = mfma16(afrag, bfrag, sacc[mt]);
        }
      }
    }
#pragma unroll
    for (int mt = 0; mt < 4; ++mt) {
      float p0[4];
#pragma unroll
      for (int r = 0; r < 4; ++r) {
        float pv = __expf(sacc[mt][r] * 0.03125f);
        p0[r] = pv;
        Ps[mt * 16 + quad * 4 + r][w * 16 + l16] = (bf16)pv;
      }
#pragma unroll
      for (int d = 1; d < 16; d <<= 1)
#pragma unroll
        for (int r = 0; r < 4; ++r) p0[r] += __shfl_xor(p0[r], d, 64);
      if (l16 == 0) {
#pragma unroll
        for (int r = 0; r < 4; ++r) atomicAdd(&Llds[mt * 16 + quad * 4 + r], p0[r]);
      }
    }
    __syncthreads();
#pragma unroll
    for (int ks2 = 0; ks2 < 4; ++ks2) {
      bf16x8 ap[4];
#pragma unroll
      for (int mt = 0; mt < 4; ++mt)
        ap[mt] = *(const bf16x8*)&Ps[mt * 16 + l16][ks2 * 32 + quad * 8];
#pragma unroll
      for (int nt = 0; nt < 8; ++nt) {
        const bf16* pv = Vt + (size_t)(w * 128 + nt * 16 + l16) * 8192
                       + c * 128 + ks2 * 32 + quad * 8;
        bf16x8 bfv = *(const bf16x8*)pv;
#pragma unroll
        for (int mt = 0; mt < 4; ++mt) oacc[mt][nt] = mfma16(ap[mt], bfv, oacc[mt][nt]);
      }
    }
    __syncthreads();
  }
#pragma unroll
  for (int mt = 0; mt < 4; ++mt) {
    float linv[4];
#pragma unroll
    for (int r = 0; r < 4; ++r) linv[r] = 1.f / Llds[mt * 16 + quad * 4 + r];
#pragma unroll
    for (int nt = 0; nt < 8; ++nt) {
      const int col = w * 128 + nt * 16 + l16;
#pragma unroll
      for (int r = 0; r < 4; ++r)
        Rb[(size_t)(qblk + mt * 16 + quad * 4 + r) * 1024 + col]
            = (bf16)(oacc[mt][nt][r] * linv[r]);
    }
  }
}

// ---------------------------------------------------------------------------
// In-place LayerNorm over last dim (1024). One block per row, 256 threads x4.
// ---------------------------------------------------------------------------
__global__ __launch_bounds__(256) void ln_kernel(
    float* __restrict__ h, const float* __restrict__ g, const float* __restrict__ b)
{
  const int tid = threadIdx.x;
  const size_t row = blockIdx.x;
  f32x4 v = *(f32x4*)&h[row * 1024 + tid * 4];
  float s1 = v[0] + v[1] + v[2] + v[3];
  float s2 = v[0]*v[0] + v[1]*v[1] + v[2]*v[2] + v[3]*v[3];
#pragma unroll
  for (int d = 1; d < 64; d <<= 1) { s1 += __shfl_xor(s1, d, 64); s2 += __shfl_xor(s2, d, 64); }
  __shared__ float a1[4], a2[4];
  const int wid = tid >> 6;
  if ((tid & 63) == 0) { a1[wid] = s1; a2[wid] = s2; }
  __syncthreads();
  s1 = a1[0] + a1[1] + a1[2] + a1[3];
  s2 = a2[0] + a2[1] + a2[2] + a2[3];
  const float mu = s1 * (1.f / 1024.f);
  const float rs = rsqrtf(s2 * (1.f / 1024.f) - mu * mu + 1e-5f);
  f32x4 gv = *(const f32x4*)&g[tid * 4];
  f32x4 bv = *(const f32x4*)&b[tid * 4];
#pragma unroll
  for (int j = 0; j < 4; ++j) v[j] = (v[j] - mu) * rs * gv[j] + bv[j];
  *(f32x4*)&h[row * 1024 + tid * 4] = v;
}

// ---------------------------------------------------------------------------
extern "C" void kernel_launch(void* const* d_in, const int* in_sizes, int n_in,
                              void* d_out, int out_size, void* d_ws, size_t ws_size,
                              hipStream_t stream)
{
  const float* x     = (const float*)d_in[0];
  const float* kbank = (const float*)d_in[1];
  const float* wq    = (const float*)d_in[2];
  const float* bq    = (const float*)d_in[3];
  const float* wk    = (const float*)d_in[4];
  const float* bk    = (const float*)d_in[5];
  const float* wv    = (const float*)d_in[6];
  const float* bv    = (const float*)d_in[7];
  const float* wf    = (const float*)d_in[8];
  const float* bf_   = (const float*)d_in[9];
  const float* gamma = (const float*)d_in[10];
  const float* beta  = (const float*)d_in[11];

  // ws layout:
  //   Qb  bf16[16384,1024]  32MB @ 0
  //   Kb  bf16[ 8192,1024]  16MB @ 32M
  //   Vt  bf16[ 1024,8192]  16MB @ 48M
  //   Rb  bf16[16384,1024]  32MB @ 64M
  //   Pb  bf16[16384,8192] 256MB @ 96M   (two-kernel attention path only)
  //   L   f32 [16384]       64KB @ 352M
  char* ws = (char*)d_ws;
  const size_t MB = 1024 * 1024;
  bf16*  Qb = (bf16*)ws;
  bf16*  Kb = (bf16*)(ws + 32 * MB);
  bf16*  Vt = (bf16*)(ws + 48 * MB);
  bf16*  Rb = (bf16*)(ws + 64 * MB);
  bf16*  Pb = (bf16*)(ws + 96 * MB);
  float* L  = (float*)(ws + 352 * MB);
  float* out = (float*)d_out;
  const bool big_ws = ws_size >= 352 * MB + 16384 * sizeof(float);

  // queries = x @ wq^T + bq
  gemm_nt<0,0,0><<<dim3(8, 128), dim3(256), 0, stream>>>(
      x, nullptr, wq, bq, nullptr, (void*)Qb, 16384, 1024, 1024);
  // keys = bank @ wk^T + bk
  gemm_nt<0,0,0><<<dim3(8, 64), dim3(256), 0, stream>>>(
      kbank, nullptr, wk, bk, nullptr, (void*)Kb, 8192, 1024, 1024);
  // Vt[d][n] = values^T: A=wv (M=1024), W=bank (N=8192), bias per-row (bv[d])
  gemm_nt<1,0,0><<<dim3(64, 8), dim3(256), 0, stream>>>(
      wv, nullptr, kbank, bv, nullptr, (void*)Vt, 1024, 8192, 1024);

  if (big_ws) {
    // Pb = exp(Qb Kb^T / 32), L[row] = sum_col Pb
    hipMemsetAsync(L, 0, 16384 * sizeof(float), stream);
    gemm_bb<0><<<dim3(64, 128), dim3(256), 0, stream>>>(Qb, Kb, Pb, L, 8192, 1024);
    // Rb = (Pb Vt^T) / L[row]
    gemm_bb<1><<<dim3(8, 128), dim3(256), 0, stream>>>(Pb, Vt, Rb, L, 1024, 8192);
  } else {
    attn_kernel<<<dim3(256), dim3(512), 0, stream>>>(Qb, Kb, Vt, Rb);
  }

  // h = [x, retrieved] @ wf^T + bf + x   -> d_out (fp32)
  gemm_nt<0,1,1><<<dim3(8, 128), dim3(256), 0, stream>>>(
      x, Rb, wf, bf_, x, (void*)out, 16384, 1024, 2048);
  // LayerNorm in place
  ln_kernel<<<dim3(16384), dim3(256), 0, stream>>>(out, gamma, beta);
}

// Round 3
// 1165.621 us; speedup vs baseline: 1.7589x; 1.7589x over previous
//
#include <hip/hip_runtime.h>

// PersistentMemory: x[16384,1024], bank[8192,1024]; all fp32 in/out.
// Round 3: attention = S-exp GEMM + PV GEMM, P chunked (4 x 4096 rows) into d_out
// (64 MB scratch, dead until concat GEMM). Rb aliases Qb (S-exp is Qb's last reader).
// Base ws need: 64 MB + 64 KB  (proven ws >= 96 MB). If ws >= 123 MB, inputs are
// pre-converted to bf16 and all GEMMs use the m97 global_load_lds structure.

typedef __bf16 bf16;
typedef __bf16 bf16x4 __attribute__((ext_vector_type(4)));
typedef __bf16 bf16x8 __attribute__((ext_vector_type(8)));
typedef float f32x4 __attribute__((ext_vector_type(4)));

static __device__ __forceinline__ f32x4 mfma16(bf16x8 a, bf16x8 b, f32x4 c) {
  return __builtin_amdgcn_mfma_f32_16x16x32_bf16(a, b, c, 0, 0, 0);
}

// async global->LDS, 16B per lane; LDS dest = wave-uniform base + lane*16
#define GLDS16(gp, lp) __builtin_amdgcn_global_load_lds( \
    (const __attribute__((address_space(1))) void*)(gp), \
    (__attribute__((address_space(3))) void*)(lp), 16, 0, 0)

// ---------------------------------------------------------------------------
// bf16 NT-GEMM, m97 structure: C[M,N]=A[M,K]@W[N,K]^T. 128x128 tile, BK=64,
// 256 thr = 4 waves (2x2, wave tile 64x64). Staging: global_load_lds width 16,
// XOR column-group swizzle (applied on the per-lane GLOBAL address) so frag
// ds_read_b128 hits the LDS bank floor.
// EPI 0: C = bf16(acc + bias[col])                       (Q, K GEMMs)
// EPI 1: C = bf16(acc + bias[row])                       (Vt GEMM)
// EPI 2: C = bf16(exp(acc/32)), rowsum atomicAdd -> L    (S-exp)
// EPI 3: C = f32(acc + bias[col] + resid[row,col])       (concat GEMM)
// CONCAT: A columns >=1024 come from A2 (both stride 1024).
// ---------------------------------------------------------------------------
template<int EPI, int CONCAT>
__global__ __launch_bounds__(256, 3) void gemm_bb(
    const bf16* __restrict__ A, const bf16* __restrict__ A2,
    const bf16* __restrict__ W, const float* __restrict__ bias,
    const float* __restrict__ resid, float* __restrict__ L,
    void* __restrict__ Cout, int N, int K)
{
  __shared__ bf16 As[128 * 64];
  __shared__ bf16 Bs[128 * 64];
  const int tid = threadIdx.x, lane = tid & 63, wid = tid >> 6;
  const int wm = (wid >> 1) * 64, wn = (wid & 1) * 64;
  const int quad = lane >> 4, l16 = lane & 15;
  const long bm = (long)blockIdx.y * 128, bn = (long)blockIdx.x * 128;

  int prow[4], pcg[4];
#pragma unroll
  for (int i = 0; i < 4; ++i) {
    int p = ((wid * 4 + i) << 6) + lane;   // 16B slot index in [0,1024)
    prow[i] = p >> 3;                      // 8 slots per 64-elem row
    pcg[i] = (p & 7) ^ (prow[i] & 7);
  }

  f32x4 acc[4][4] = {};

  for (int k0 = 0; k0 < K; k0 += 64) {
    const bf16* Asrc = (CONCAT && k0 >= 1024) ? A2 : A;
    const int kA = (CONCAT && k0 >= 1024) ? k0 - 1024 : k0;
    const int lda = CONCAT ? 1024 : K;
    __syncthreads();   // previous iteration's frag reads done before overwrite
#pragma unroll
    for (int i = 0; i < 4; ++i) {
      const bf16* ga = Asrc + (size_t)(bm + prow[i]) * lda + kA + pcg[i] * 8;
      GLDS16(ga, (char*)As + ((wid * 4 + i) << 10));
    }
#pragma unroll
    for (int i = 0; i < 4; ++i) {
      const bf16* gb = W + (size_t)(bn + prow[i]) * K + k0 + pcg[i] * 8;
      GLDS16(gb, (char*)Bs + ((wid * 4 + i) << 10));
    }
    __syncthreads();   // staging complete (vmcnt drained before barrier)
#pragma unroll
    for (int kk = 0; kk < 2; ++kk) {
      bf16x8 af[4], bfv[4];
#pragma unroll
      for (int mt = 0; mt < 4; ++mt) {
        const int r = wm + mt * 16 + l16;
        af[mt] = *(const bf16x8*)((const char*)As + (r << 7)
                                  + ((((kk << 2) + quad) ^ (r & 7)) << 4));
      }
#pragma unroll
      for (int nt = 0; nt < 4; ++nt) {
        const int r = wn + nt * 16 + l16;
        bfv[nt] = *(const bf16x8*)((const char*)Bs + (r << 7)
                                   + ((((kk << 2) + quad) ^ (r & 7)) << 4));
      }
#pragma unroll
      for (int mt = 0; mt < 4; ++mt)
#pragma unroll
        for (int nt = 0; nt < 4; ++nt)
          acc[mt][nt] = mfma16(af[mt], bfv[nt], acc[mt][nt]);
    }
  }

#pragma unroll
  for (int mt = 0; mt < 4; ++mt) {
    const long row0 = bm + wm + mt * 16 + quad * 4;
    if (EPI == 2) {
      float rsum[4] = {0.f, 0.f, 0.f, 0.f};
#pragma unroll
      for (int nt = 0; nt < 4; ++nt) {
        const long col = bn + wn + nt * 16 + l16;
#pragma unroll
        for (int r = 0; r < 4; ++r) {
          float p = __expf(acc[mt][nt][r] * 0.03125f);
          rsum[r] += p;
          ((bf16*)Cout)[(size_t)(row0 + r) * N + col] = (bf16)p;
        }
      }
#pragma unroll
      for (int s = 1; s < 16; s <<= 1)
#pragma unroll
        for (int r = 0; r < 4; ++r) rsum[r] += __shfl_xor(rsum[r], s, 64);
      if (l16 == 0) {
#pragma unroll
        for (int r = 0; r < 4; ++r) atomicAdd(&L[row0 + r], rsum[r]);
      }
    } else {
#pragma unroll
      for (int nt = 0; nt < 4; ++nt) {
        const long col = bn + wn + nt * 16 + l16;
        const float bc = (EPI == 1) ? 0.f : bias[col];
#pragma unroll
        for (int r = 0; r < 4; ++r) {
          float v = acc[mt][nt][r] + ((EPI == 1) ? bias[row0 + r] : bc);
          if (EPI == 3) {
            v += resid[(size_t)(row0 + r) * 1024 + col];
            ((float*)Cout)[(size_t)(row0 + r) * N + col] = v;
          } else {
            ((bf16*)Cout)[(size_t)(row0 + r) * N + col] = (bf16)v;
          }
        }
      }
    }
  }
}

// ---------------------------------------------------------------------------
// PV GEMM: Rb[M,1024] = (P[M,8192] @ Vt[1024,8192]^T) / L[row].  512 thr =
// 8 waves (4 m-groups x 2 n-groups; wave tile 32x64), 128x128 tile, BK=128
// (grid is 1 block/CU; BK=128 halves barrier drains at no occupancy cost).
// ---------------------------------------------------------------------------
__global__ __launch_bounds__(512, 2) void pv_gemm(
    const bf16* __restrict__ P, const bf16* __restrict__ Vt,
    const float* __restrict__ L, bf16* __restrict__ Rb)
{
  __shared__ bf16 As[128 * 128];
  __shared__ bf16 Bs[128 * 128];
  const int tid = threadIdx.x, lane = tid & 63, wid = tid >> 6;
  const int wm = (wid & 3) * 32, wn = (wid >> 2) * 64;
  const int quad = lane >> 4, l16 = lane & 15;
  const long bm = (long)blockIdx.y * 128, bn = (long)blockIdx.x * 128;

  int prow[4], pcg[4];
#pragma unroll
  for (int i = 0; i < 4; ++i) {
    int p = ((wid * 4 + i) << 6) + lane;   // 16B slot in [0,2048)
    prow[i] = p >> 4;                      // 16 slots per 128-elem row
    pcg[i] = (p & 15) ^ (prow[i] & 15);
  }

  f32x4 acc[2][4] = {};

  for (int k0 = 0; k0 < 8192; k0 += 128) {
    __syncthreads();
#pragma unroll
    for (int i = 0; i < 4; ++i)
      GLDS16(P + (size_t)(bm + prow[i]) * 8192 + k0 + pcg[i] * 8,
             (char*)As + ((wid * 4 + i) << 10));
#pragma unroll
    for (int i = 0; i < 4; ++i)
      GLDS16(Vt + (size_t)(bn + prow[i]) * 8192 + k0 + pcg[i] * 8,
             (char*)Bs + ((wid * 4 + i) << 10));
    __syncthreads();
#pragma unroll
    for (int kk = 0; kk < 4; ++kk) {
      bf16x8 af[2], bfv[4];
#pragma unroll
      for (int mt = 0; mt < 2; ++mt) {
        const int r = wm + mt * 16 + l16;
        af[mt] = *(const bf16x8*)((const char*)As + (r << 8)
                                  + ((((kk << 2) + quad) ^ (r & 15)) << 4));
      }
#pragma unroll
      for (int nt = 0; nt < 4; ++nt) {
        const int r = wn + nt * 16 + l16;
        bfv[nt] = *(const bf16x8*)((const char*)Bs + (r << 8)
                                   + ((((kk << 2) + quad) ^ (r & 15)) << 4));
      }
#pragma unroll
      for (int mt = 0; mt < 2; ++mt)
#pragma unroll
        for (int nt = 0; nt < 4; ++nt)
          acc[mt][nt] = mfma16(af[mt], bfv[nt], acc[mt][nt]);
    }
  }

#pragma unroll
  for (int mt = 0; mt < 2; ++mt) {
    const long row0 = bm + wm + mt * 16 + quad * 4;
    float linv[4];
#pragma unroll
    for (int r = 0; r < 4; ++r) linv[r] = 1.f / L[row0 + r];
#pragma unroll
    for (int nt = 0; nt < 4; ++nt) {
      const long col = bn + wn + nt * 16 + l16;
#pragma unroll
      for (int r = 0; r < 4; ++r)
        Rb[(size_t)(row0 + r) * 1024 + col] = (bf16)(acc[mt][nt][r] * linv[r]);
    }
  }
}

// ---------------------------------------------------------------------------
// fp32-input NT-GEMM (small-ws path only): C[M,N] = A[M,K] @ W[N,K]^T (+bias).
// ---------------------------------------------------------------------------
template<int BIAS_ROW, int OUT_F32_RES, int CONCAT>
__global__ __launch_bounds__(256, 3) void gemm_nt(
    const float* __restrict__ A, const bf16* __restrict__ A2,
    const float* __restrict__ W, const float* __restrict__ bias,
    const float* __restrict__ resid, void* __restrict__ Cout,
    int M, int N, int K)
{
  __shared__ bf16 As[128][72];
  __shared__ bf16 Bs[128][72];
  const int tid  = threadIdx.x;
  const int lane = tid & 63;
  const int wid  = tid >> 6;
  const int wm   = (wid >> 1) * 64, wn = (wid & 1) * 64;
  const int quad = lane >> 4, l16 = lane & 15;
  const long bm = (long)blockIdx.y * 128, bn = (long)blockIdx.x * 128;
  const int r0 = tid >> 2, cq = (tid & 3) * 16;
  const int lda = CONCAT ? 1024 : K;

  f32x4 acc[4][4] = {};

  for (int k0 = 0; k0 < K; k0 += 64) {
    const bool useb = CONCAT && (k0 >= 1024);
    const int kA = useb ? (k0 - 1024) : k0;
    f32x4 va[2][4], vb[2][4];
    bf16x8 ra[2][2];
    if (useb) {
#pragma unroll
      for (int g = 0; g < 2; ++g) {
        const bf16* p = A2 + (size_t)(bm + r0 + 64 * g) * 1024 + kA + cq;
        ra[g][0] = *(const bf16x8*)p;
        ra[g][1] = *(const bf16x8*)(p + 8);
      }
    } else {
#pragma unroll
      for (int g = 0; g < 2; ++g) {
        const f32x4* p = (const f32x4*)(A + (size_t)(bm + r0 + 64 * g) * lda + kA + cq);
#pragma unroll
        for (int j = 0; j < 4; ++j) va[g][j] = p[j];
      }
    }
#pragma unroll
    for (int g = 0; g < 2; ++g) {
      const f32x4* p = (const f32x4*)(W + (size_t)(bn + r0 + 64 * g) * K + k0 + cq);
#pragma unroll
      for (int j = 0; j < 4; ++j) vb[g][j] = p[j];
    }
    __syncthreads();
#pragma unroll
    for (int g = 0; g < 2; ++g) {
      bf16* dA = &As[r0 + 64 * g][cq];
      if (useb) {
        *(bf16x8*)dA = ra[g][0]; *(bf16x8*)(dA + 8) = ra[g][1];
      } else {
        bf16x8 t0, t1;
#pragma unroll
        for (int j = 0; j < 4; ++j) {
          t0[j] = (bf16)va[g][0][j]; t0[4 + j] = (bf16)va[g][1][j];
          t1[j] = (bf16)va[g][2][j]; t1[4 + j] = (bf16)va[g][3][j];
        }
        *(bf16x8*)dA = t0; *(bf16x8*)(dA + 8) = t1;
      }
      bf16* dB = &Bs[r0 + 64 * g][cq];
      bf16x8 u0, u1;
#pragma unroll
      for (int j = 0; j < 4; ++j) {
        u0[j] = (bf16)vb[g][0][j]; u0[4 + j] = (bf16)vb[g][1][j];
        u1[j] = (bf16)vb[g][2][j]; u1[4 + j] = (bf16)vb[g][3][j];
      }
      *(bf16x8*)dB = u0; *(bf16x8*)(dB + 8) = u1;
    }
    __syncthreads();
#pragma unroll
    for (int kk = 0; kk < 2; ++kk) {
      bf16x8 af[4], bfv[4];
#pragma unroll
      for (int mt = 0; mt < 4; ++mt)
        af[mt] = *(const bf16x8*)&As[wm + mt * 16 + l16][kk * 32 + quad * 8];
#pragma unroll
      for (int nt = 0; nt < 4; ++nt)
        bfv[nt] = *(const bf16x8*)&Bs[wn + nt * 16 + l16][kk * 32 + quad * 8];
#pragma unroll
      for (int mt = 0; mt < 4; ++mt)
#pragma unroll
        for (int nt = 0; nt < 4; ++nt)
          acc[mt][nt] = mfma16(af[mt], bfv[nt], acc[mt][nt]);
    }
  }
#pragma unroll
  for (int mt = 0; mt < 4; ++mt) {
    const long row0 = bm + wm + mt * 16 + quad * 4;
#pragma unroll
    for (int nt = 0; nt < 4; ++nt) {
      const long col = bn + wn + nt * 16 + l16;
      const float bc = BIAS_ROW ? 0.f : bias[col];
#pragma unroll
      for (int r = 0; r < 4; ++r) {
        float v = acc[mt][nt][r] + (BIAS_ROW ? bias[row0 + r] : bc);
        if (OUT_F32_RES) {
          v += resid[(size_t)(row0 + r) * 1024 + col];
          ((float*)Cout)[(size_t)(row0 + r) * N + col] = v;
        } else {
          ((bf16*)Cout)[(size_t)(row0 + r) * N + col] = (bf16)v;
        }
      }
    }
  }
}

// ---------------------------------------------------------------------------
// fp32 -> bf16 bulk convert of the six read-only inputs (big-ws path).
// One f32x4 per thread; segment bounds in float4 units.
// ---------------------------------------------------------------------------
__global__ __launch_bounds__(256) void cvt6(
    const float* __restrict__ x, const float* __restrict__ bank,
    const float* __restrict__ wq, const float* __restrict__ wk,
    const float* __restrict__ wv, const float* __restrict__ wf,
    bf16* __restrict__ xb, bf16* __restrict__ bankb,
    bf16* __restrict__ wqb, bf16* __restrict__ wkb,
    bf16* __restrict__ wvb, bf16* __restrict__ wfb)
{
  long i4 = (long)blockIdx.x * 256 + threadIdx.x;
  const float* src; bf16* dst; long off;
  if      (i4 < 4194304) { src = x;    dst = xb;    off = i4; }
  else if (i4 < 6291456) { src = bank; dst = bankb; off = i4 - 4194304; }
  else if (i4 < 6553600) { src = wq;   dst = wqb;   off = i4 - 6291456; }
  else if (i4 < 6815744) { src = wk;   dst = wkb;   off = i4 - 6553600; }
  else if (i4 < 7077888) { src = wv;   dst = wvb;   off = i4 - 6815744; }
  else if (i4 < 7602176) { src = wf;   dst = wfb;   off = i4 - 7077888; }
  else return;
  f32x4 v = ((const f32x4*)src)[off];
  bf16x4 o;
#pragma unroll
  for (int j = 0; j < 4; ++j) o[j] = (bf16)v[j];
  ((bf16x4*)dst)[off] = o;
}

__global__ __launch_bounds__(256) void zerof(float* __restrict__ p) {
  p[(size_t)blockIdx.x * 256 + threadIdx.x] = 0.f;
}

// ---------------------------------------------------------------------------
// In-place LayerNorm over last dim (1024). One block per row, 256 threads x4.
// ---------------------------------------------------------------------------
__global__ __launch_bounds__(256) void ln_kernel(
    float* __restrict__ h, const float* __restrict__ g, const float* __restrict__ b)
{
  const int tid = threadIdx.x;
  const size_t row = blockIdx.x;
  f32x4 v = *(f32x4*)&h[row * 1024 + tid * 4];
  float s1 = v[0] + v[1] + v[2] + v[3];
  float s2 = v[0]*v[0] + v[1]*v[1] + v[2]*v[2] + v[3]*v[3];
#pragma unroll
  for (int d = 1; d < 64; d <<= 1) { s1 += __shfl_xor(s1, d, 64); s2 += __shfl_xor(s2, d, 64); }
  __shared__ float a1[4], a2[4];
  const int wid = tid >> 6;
  if ((tid & 63) == 0) { a1[wid] = s1; a2[wid] = s2; }
  __syncthreads();
  s1 = a1[0] + a1[1] + a1[2] + a1[3];
  s2 = a2[0] + a2[1] + a2[2] + a2[3];
  const float mu = s1 * (1.f / 1024.f);
  const float rs = rsqrtf(s2 * (1.f / 1024.f) - mu * mu + 1e-5f);
  f32x4 gv = *(const f32x4*)&g[tid * 4];
  f32x4 bv = *(const f32x4*)&b[tid * 4];
#pragma unroll
  for (int j = 0; j < 4; ++j) v[j] = (v[j] - mu) * rs * gv[j] + bv[j];
  *(f32x4*)&h[row * 1024 + tid * 4] = v;
}

// ---------------------------------------------------------------------------
extern "C" void kernel_launch(void* const* d_in, const int* in_sizes, int n_in,
                              void* d_out, int out_size, void* d_ws, size_t ws_size,
                              hipStream_t stream)
{
  const float* x     = (const float*)d_in[0];
  const float* kbank = (const float*)d_in[1];
  const float* wq    = (const float*)d_in[2];
  const float* bq    = (const float*)d_in[3];
  const float* wk    = (const float*)d_in[4];
  const float* bk    = (const float*)d_in[5];
  const float* wv    = (const float*)d_in[6];
  const float* bv    = (const float*)d_in[7];
  const float* wf    = (const float*)d_in[8];
  const float* bf_   = (const float*)d_in[9];
  const float* gamma = (const float*)d_in[10];
  const float* beta  = (const float*)d_in[11];

  // ws layout (MB offsets):
  //   [0,32)   Qb bf16[16384,1024]  -> later aliased as Rb (retrieved)
  //   [32,48)  Kb bf16[8192,1024]
  //   [48,64)  Vt bf16[1024,8192]
  //   [64,+64K) L f32[16384]
  //   big path (ws >= 123 MB):
  //   [65,97)  xb   [97,113) bankb  [113,117) wfb  [117,119) wqb
  //   [119,121) wkb [121,123) wvb
  // P (bf16, 4096x8192 per chunk) lives in d_out (64 MB), dead until concat GEMM.
  char* ws = (char*)d_ws;
  const size_t MB = 1024 * 1024;
  bf16*  Qb    = (bf16*)ws;
  bf16*  Rb    = Qb;                       // alias: PV writes after S-exp reads
  bf16*  Kb    = (bf16*)(ws + 32 * MB);
  bf16*  Vt    = (bf16*)(ws + 48 * MB);
  float* L     = (float*)(ws + 64 * MB);
  bf16*  xb    = (bf16*)(ws + 65 * MB);
  bf16*  bankb = (bf16*)(ws + 97 * MB);
  bf16*  wfb   = (bf16*)(ws + 113 * MB);
  bf16*  wqb   = (bf16*)(ws + 117 * MB);
  bf16*  wkb   = (bf16*)(ws + 119 * MB);
  bf16*  wvb   = (bf16*)(ws + 121 * MB);
  bf16*  P     = (bf16*)d_out;
  float* out   = (float*)d_out;
  const bool big = ws_size >= 123 * MB;

  if (big) {
    cvt6<<<dim3(29696), dim3(256), 0, stream>>>(
        x, kbank, wq, wk, wv, wf, xb, bankb, wqb, wkb, wvb, wfb);
    gemm_bb<0,0><<<dim3(8, 128), dim3(256), 0, stream>>>(
        xb, nullptr, wqb, bq, nullptr, nullptr, (void*)Qb, 1024, 1024);
    gemm_bb<0,0><<<dim3(8, 64), dim3(256), 0, stream>>>(
        bankb, nullptr, wkb, bk, nullptr, nullptr, (void*)Kb, 1024, 1024);
    gemm_bb<1,0><<<dim3(64, 8), dim3(256), 0, stream>>>(
        wvb, nullptr, bankb, bv, nullptr, nullptr, (void*)Vt, 8192, 1024);
  } else {
    gemm_nt<0,0,0><<<dim3(8, 128), dim3(256), 0, stream>>>(
        x, nullptr, wq, bq, nullptr, (void*)Qb, 16384, 1024, 1024);
    gemm_nt<0,0,0><<<dim3(8, 64), dim3(256), 0, stream>>>(
        kbank, nullptr, wk, bk, nullptr, (void*)Kb, 8192, 1024, 1024);
    gemm_nt<1,0,0><<<dim3(64, 8), dim3(256), 0, stream>>>(
        wv, nullptr, kbank, bv, nullptr, (void*)Vt, 1024, 8192, 1024);
  }

  zerof<<<dim3(64), dim3(256), 0, stream>>>(L);
  for (int c = 0; c < 4; ++c) {
    // P = exp(Q_chunk Kb^T / 32) into d_out; rowsums -> L
    gemm_bb<2,0><<<dim3(64, 32), dim3(256), 0, stream>>>(
        Qb + (size_t)c * 4096 * 1024, nullptr, Kb, nullptr, nullptr,
        L + c * 4096, (void*)P, 8192, 1024);
    // Rb_chunk = (P Vt^T) / L   (overwrites Qb chunk c, already consumed)
    pv_gemm<<<dim3(8, 32), dim3(512), 0, stream>>>(
        P, Vt, L + c * 4096, Rb + (size_t)c * 4096 * 1024);
  }

  // h = [x, retrieved] @ wf^T + bf + x -> d_out (fp32); P fully dead now
  if (big) {
    gemm_bb<3,1><<<dim3(8, 128), dim3(256), 0, stream>>>(
        xb, Rb, wfb, bf_, x, nullptr, (void*)out, 1024, 2048);
  } else {
    gemm_nt<0,1,1><<<dim3(8, 128), dim3(256), 0, stream>>>(
        x, Rb, wf, bf_, x, (void*)out, 16384, 1024, 2048);
  }
  ln_kernel<<<dim3(16384), dim3(256), 0, stream>>>(out, gamma, beta);
}